// Round 1
// baseline (40676.404 us; speedup 1.0000x reference)
//
#include <hip/hip_runtime.h>

// ============================================================================
// AgnisV5: sequential recurrence (4-phase persistent kernel, weights in LDS)
//          + deferred batched lm_head GEMM (bf16 MFMA).
//
// Weight fusions (precomputed per call):
//   RV0 = R@V0, RWt = R@Wt, W2G = W2@Wg_bot, gbias = c2@Wg_bot
//   embV0[t] = emb_t@V0 + b0, embWg[t] = emb_t@Wg_top + bg   (token-only)
// Per step (4 grid-wide flag syncs):
//   P1: a1 = gelu(embV0 + 0.4*h@RV0), tf = h@RWt        (h recomputed redundantly)
//   P2: target = gelu(a1@V1 + b1)
//   P3: x2 EMA(10 iters), cb = 0.5(l2n(tg)+l2n(x2)), u = gelu(cb@W1+c1)
//   P4: cf = u@W2+c2, gv = embWg + u@W2G + gbias
// h_t = LN(sig(gv)*(cf+0.4tf) + (1-sig)*emb) recomputed by all WGs at next P1.
// ============================================================================

typedef __attribute__((ext_vector_type(8))) short short8;
typedef __attribute__((ext_vector_type(4))) float f32x4;

__device__ __forceinline__ unsigned short f2b(float f){
  unsigned int u = __builtin_bit_cast(unsigned int, f);
  u += 0x7fffu + ((u >> 16) & 1u);
  return (unsigned short)(u >> 16);
}
__device__ __forceinline__ float b2f(unsigned short v){
  return __builtin_bit_cast(float, ((unsigned int)v) << 16);
}
__device__ __forceinline__ float geluf(float x){
  return 0.5f * x * (1.0f + erff(x * 0.70710678118654752440f));
}
__device__ __forceinline__ void unp4(uint2 q, float* o){
  o[0] = b2f((unsigned short)(q.x & 0xffffu));
  o[1] = b2f((unsigned short)(q.x >> 16));
  o[2] = b2f((unsigned short)(q.y & 0xffffu));
  o[3] = b2f((unsigned short)(q.y >> 16));
}
__device__ __forceinline__ float wsum(float v){
  #pragma unroll
  for (int o = 32; o; o >>= 1) v += __shfl_xor(v, o, 64);
  return v;
}

// ---------------------------------------------------------------------------
// transpose + f32->bf16 : src [768, N] (rows offset by rowoff) -> dst [N, 768]
// ---------------------------------------------------------------------------
__global__ __launch_bounds__(256) void transpose_f2b(
    const float* __restrict__ src, unsigned short* __restrict__ dst,
    int N, int rowoff)
{
  __shared__ unsigned short tile[32][33];
  const int nb = blockIdx.x * 32, kb = blockIdx.y * 32;
  const int tx = threadIdx.x & 31, ty = threadIdx.x >> 5;
  #pragma unroll
  for (int i = 0; i < 4; ++i) {
    int k = kb + ty + 8*i, n = nb + tx;
    unsigned short v = 0;
    if (n < N) v = f2b(src[(size_t)(rowoff + k)*N + n]);
    tile[ty + 8*i][tx] = v;
  }
  __syncthreads();
  #pragma unroll
  for (int i = 0; i < 4; ++i) {
    int n = nb + ty + 8*i;
    if (n < N) dst[(size_t)n*768 + kb + tx] = tile[tx][ty + 8*i];
  }
}

// ---------------------------------------------------------------------------
// embedding gather + L2 normalize : emb_all[b*256+t][768]
// ---------------------------------------------------------------------------
__global__ __launch_bounds__(256) void embed_kernel(
    const int* __restrict__ tok, const float* __restrict__ emb,
    float* __restrict__ emb_all)
{
  const int row = blockIdx.x, tid = threadIdx.x;
  const int id = tok[row];
  const float* e = emb + (size_t)id * 768;
  float v0 = e[tid], v1 = e[tid+256], v2 = e[tid+512];
  float ssq = wsum(v0*v0 + v1*v1 + v2*v2);
  __shared__ float red[4];
  if ((tid & 63) == 0) red[tid >> 6] = ssq;
  __syncthreads();
  float inv = 1.0f / fmaxf(sqrtf(red[0]+red[1]+red[2]+red[3]), 1e-12f);
  float* o = emb_all + (size_t)row * 768;
  o[tid] = v0*inv; o[tid+256] = v1*inv; o[tid+512] = v2*inv;
}

// gbias[c] = sum_k c2[k] * Wg[768+k][c]
__global__ void gbias_kernel(const float* __restrict__ c2,
                             const float* __restrict__ Wg,
                             float* __restrict__ gbias)
{
  int c = blockIdx.x * 256 + threadIdx.x;
  if (c >= 768) return;
  float s = 0.f;
  for (int k = 0; k < 768; ++k) s += c2[k] * Wg[(size_t)(768 + k)*768 + c];
  gbias[c] = s;
}

// ---------------------------------------------------------------------------
// GEMM: C[M,N] = A[M,768](f32, bf16-cast) @ B + bias
//   BMODE 0: B = BT bf16 [N,768] (transposed)   BMODE 1: B = f32 [768,N]
// 64x64 tile/WG, mfma_f32_16x16x32_bf16, XCD-partitioned grid over N-tiles.
// ---------------------------------------------------------------------------
template<int BMODE>
__global__ __launch_bounds__(256) void gemm_kernel(
    const float* __restrict__ A, const void* __restrict__ Bp,
    float* __restrict__ C, const float* __restrict__ bias,
    int M, int N, int q, int r)
{
  const int x = blockIdx.x;             // xcd slot (blockIdx round-robins XCDs)
  const int s = blockIdx.y;
  const int mtiles = M >> 6;
  const int cnt_x = q + (x < r ? 1 : 0);
  if (s >= cnt_x * mtiles) return;
  const int off_x = x*q + (x < r ? x : r);
  const int nt = off_x + s / mtiles;
  const int mt = s % mtiles;
  const int m0 = mt << 6, n0 = nt << 6;
  const int w = threadIdx.x >> 6, l = threadIdx.x & 63;
  const int lrow = l & 15, lk8 = (l >> 4) << 3;
  const int arow = m0 + w*16 + lrow;
  f32x4 acc[4] = {f32x4{0,0,0,0}, f32x4{0,0,0,0}, f32x4{0,0,0,0}, f32x4{0,0,0,0}};
  const unsigned short* BT = (const unsigned short*)Bp;
  const float* Bf = (const float*)Bp;

  for (int kk = 0; kk < 768; kk += 32) {
    const float4* ap = (const float4*)(A + (size_t)arow*768 + kk + lk8);
    float4 a0 = ap[0], a1 = ap[1];
    short8 af;
    af[0]=(short)f2b(a0.x); af[1]=(short)f2b(a0.y); af[2]=(short)f2b(a0.z); af[3]=(short)f2b(a0.w);
    af[4]=(short)f2b(a1.x); af[5]=(short)f2b(a1.y); af[6]=(short)f2b(a1.z); af[7]=(short)f2b(a1.w);
    #pragma unroll
    for (int ss = 0; ss < 4; ++ss) {
      const int col = n0 + ss*16 + lrow;
      short8 bf;
      if (BMODE == 0) {
        if (col < N) {
          uint4 raw = *(const uint4*)(BT + (size_t)col*768 + kk + lk8);
          bf = __builtin_bit_cast(short8, raw);
        } else {
          bf = short8{0,0,0,0,0,0,0,0};
        }
      } else {
        #pragma unroll
        for (int j = 0; j < 8; ++j) {
          float v = (col < N) ? Bf[(size_t)(kk + lk8 + j)*N + col] : 0.f;
          bf[j] = (short)f2b(v);
        }
      }
      acc[ss] = __builtin_amdgcn_mfma_f32_16x16x32_bf16(af, bf, acc[ss], 0, 0, 0);
    }
  }
  const int rbase = m0 + w*16 + ((l >> 4) << 2);
  #pragma unroll
  for (int ss = 0; ss < 4; ++ss) {
    const int col = n0 + ss*16 + lrow;
    if (col < N) {
      const float badd = bias ? bias[col] : 0.f;
      #pragma unroll
      for (int rr = 0; rr < 4; ++rr)
        C[(size_t)(rbase + rr)*N + col] = acc[ss][rr] + badd;
    }
  }
}

// ---------------------------------------------------------------------------
// Persistent recurrent kernel: 256 WGs (1/CU), 256 threads.
// WG g owns cols [g*12,+12) of RV0 and [g*3,+3) of V1/W1/W2/W2G/RWt in LDS.
// Flag sync: flg[phase*256 + g] = t+1 after WG g finishes phase at step t.
// ---------------------------------------------------------------------------
__global__ __launch_bounds__(256) void recur_kernel(
    const float* __restrict__ RV0, const float* __restrict__ RWt,
    const float* __restrict__ W1,  const float* __restrict__ W2,
    const float* __restrict__ W2G, const float* __restrict__ V1,
    const float* __restrict__ embV0, const float* __restrict__ embWg,
    const float* __restrict__ gbias, const float* __restrict__ emb_all,
    const float* __restrict__ b1, const float* __restrict__ c1,
    const float* __restrict__ c2, const float* __restrict__ gam,
    const float* __restrict__ bet, float* __restrict__ h_all,
    unsigned short* __restrict__ a1buf, unsigned short* __restrict__ tfbuf,
    unsigned short* __restrict__ tgbuf, unsigned short* __restrict__ ubuf,
    unsigned short* __restrict__ cfbuf, unsigned short* __restrict__ gvbuf,
    int* __restrict__ flg)
{
  __shared__ float sRV0[12*768];        // 36864 B
  __shared__ float sV1[3*3072];         // 36864 B
  __shared__ float sW1[3*768];
  __shared__ float sW2[3*768];
  __shared__ float sW2G[3*768];
  __shared__ float sRWt[3*768];         // 4 x 9216 B
  __shared__ float sX[4*768];           // 12288 B (h / cb / u)
  __shared__ float sX2[4*768];          // 12288 B (x2 state, replicated)
  __shared__ uint4 sA1q[1536];          // 24576 B (a1 bf16 staged)
  __shared__ float sRed[256];           // 1024 B   -- total 160768 B
  unsigned short* sA1 = (unsigned short*)sA1q;

  const int g = blockIdx.x, tid = threadIdx.x;
  const int wv = tid >> 6, lane = tid & 63;

  // ---- load weight slices into LDS ----
  for (int i = tid; i < 12*768; i += 256) {
    int k = i / 12, c = i - k*12;
    sRV0[c*768 + k] = RV0[(size_t)k*3072 + g*12 + c];
  }
  for (int i = tid; i < 3*3072; i += 256) {
    int k = i / 3, c = i - k*3;
    sV1[c*3072 + k] = V1[(size_t)k*768 + g*3 + c];
  }
  for (int i = tid; i < 3*768; i += 256) {
    int k = i / 3, c = i - k*3;
    const int gc = g*3 + c;
    sW1[c*768 + k]  = W1[(size_t)k*768 + gc];
    sW2[c*768 + k]  = W2[(size_t)k*768 + gc];
    sW2G[c*768 + k] = W2G[(size_t)k*768 + gc];
    sRWt[c*768 + k] = RWt[(size_t)k*768 + gc];
  }
  for (int i = tid; i < 4*768; i += 256) sX2[i] = 0.f;
  __syncthreads();

  int* fP1 = flg;
  int* fP2 = flg + 256;
  int* fP3 = flg + 512;
  int* fP4 = flg + 768;

  for (int t = 0; t <= 256; ++t) {
    // ================= h_{t-1} (redundant in every WG) =================
    if (t == 0) {
      for (int i = tid; i < 4*768; i += 256) sX[i] = 0.f;
    } else {
      {
        int* p = fP4 + tid;
        while (__hip_atomic_load(p, __ATOMIC_RELAXED, __HIP_MEMORY_SCOPE_AGENT) < t)
          __builtin_amdgcn_s_sleep(1);
      }
      __syncthreads();
      __threadfence();
      const int par = (t - 1) & 1;
      const int base = par*3072 + wv*768 + lane*12;
      float cfv[12], gvv[12], tfv[12], emv[12], pre[12];
      {
        const uint2* p;
        p = (const uint2*)(cfbuf + base); unp4(p[0],cfv); unp4(p[1],cfv+4); unp4(p[2],cfv+8);
        p = (const uint2*)(gvbuf + base); unp4(p[0],gvv); unp4(p[1],gvv+4); unp4(p[2],gvv+8);
        p = (const uint2*)(tfbuf + base); unp4(p[0],tfv); unp4(p[1],tfv+4); unp4(p[2],tfv+8);
        const float4* q4 = (const float4*)(emb_all + (size_t)(wv*256 + t - 1)*768 + lane*12);
        float4 e0 = q4[0], e1 = q4[1], e2 = q4[2];
        emv[0]=e0.x; emv[1]=e0.y; emv[2]=e0.z; emv[3]=e0.w;
        emv[4]=e1.x; emv[5]=e1.y; emv[6]=e1.z; emv[7]=e1.w;
        emv[8]=e2.x; emv[9]=e2.y; emv[10]=e2.z; emv[11]=e2.w;
      }
      float s1 = 0.f;
      #pragma unroll
      for (int i = 0; i < 12; ++i) {
        const float gg = 1.0f / (1.0f + expf(-gvv[i]));
        pre[i] = gg*(cfv[i] + 0.4f*tfv[i]) + (1.0f - gg)*emv[i];
        s1 += pre[i];
      }
      s1 = wsum(s1);
      const float mean = s1 * (1.0f/768.0f);
      float s2 = 0.f;
      #pragma unroll
      for (int i = 0; i < 12; ++i) { const float d = pre[i] - mean; s2 += d*d; }
      s2 = wsum(s2);
      const float rstd = 1.0f / sqrtf(s2*(1.0f/768.0f) + 1e-5f);
      const int k0 = lane*12;
      float hv[12];
      #pragma unroll
      for (int i = 0; i < 12; ++i) {
        hv[i] = (pre[i] - mean)*rstd*gam[k0+i] + bet[k0+i];
        sX[wv*768 + k0 + i] = hv[i];
      }
      if (g == 0) {
        float* hp = h_all + (size_t)(wv*256 + t - 1)*768 + k0;
        #pragma unroll
        for (int i = 0; i < 12; ++i) hp[i] = hv[i];
      }
    }
    __syncthreads();
    if (t == 256) break;
    const int par = t & 1;

    // ================= P1: a1 slice, tf slice =================
    {
      const int cg = tid >> 6, ks = tid & 63;
      float acc[4][4] = {};
      for (int i = 0; i < 12; ++i) {
        const int k = ks + 64*i;
        const float x0 = sX[k], x1 = sX[768+k], x2v = sX[1536+k], x3 = sX[2304+k];
        #pragma unroll
        for (int j = 0; j < 4; ++j) {
          float w;
          if (cg < 3) w = sRV0[(cg*4 + j)*768 + k];
          else        w = (j < 3) ? sRWt[j*768 + k] : 0.f;
          acc[j][0] += w*x0; acc[j][1] += w*x1; acc[j][2] += w*x2v; acc[j][3] += w*x3;
        }
      }
      #pragma unroll
      for (int j = 0; j < 4; ++j)
        #pragma unroll
        for (int bb = 0; bb < 4; ++bb) {
          const float v = wsum(acc[j][bb]);
          if (lane == 0) sRed[cg*16 + j*4 + bb] = v;
        }
      __syncthreads();
      if (tid < 60) {
        const int c = tid >> 2, bb = tid & 3;
        const float v = sRed[(c >> 2)*16 + (c & 3)*4 + bb];
        if (c < 12) {
          const int gc = g*12 + c;
          const float a = embV0[(size_t)(bb*256 + t)*3072 + gc] + 0.4f*v;
          a1buf[par*12288 + bb*3072 + gc] = f2b(geluf(a));
        } else {
          const int gc = g*3 + (c - 12);
          tfbuf[par*3072 + bb*768 + gc] = f2b(v);
        }
      }
      __threadfence();
      __syncthreads();
      if (tid == 0)
        __hip_atomic_store(fP1 + g, t + 1, __ATOMIC_RELAXED, __HIP_MEMORY_SCOPE_AGENT);
    }

    // ================= P2: target slice =================
    {
      {
        int* p = fP1 + tid;
        while (__hip_atomic_load(p, __ATOMIC_RELAXED, __HIP_MEMORY_SCOPE_AGENT) < t + 1)
          __builtin_amdgcn_s_sleep(1);
      }
      __syncthreads();
      __threadfence();
      {
        const uint4* srcp = (const uint4*)(a1buf + par*12288);
        for (int i = tid; i < 1536; i += 256) sA1q[i] = srcp[i];
      }
      __syncthreads();
      const int ks = lane, isub = wv;
      float acc[3][4] = {};
      for (int ip = 0; ip < 12; ++ip) {
        const int k = ks + 64*(isub + 4*ip);
        float xv[4];
        #pragma unroll
        for (int bb = 0; bb < 4; ++bb) xv[bb] = b2f(sA1[bb*3072 + k]);
        #pragma unroll
        for (int c = 0; c < 3; ++c) {
          const float w = sV1[c*3072 + k];
          acc[c][0] += w*xv[0]; acc[c][1] += w*xv[1]; acc[c][2] += w*xv[2]; acc[c][3] += w*xv[3];
        }
      }
      #pragma unroll
      for (int c = 0; c < 3; ++c)
        #pragma unroll
        for (int bb = 0; bb < 4; ++bb) {
          const float v = wsum(acc[c][bb]);
          if (lane == 0) sRed[isub*12 + c*4 + bb] = v;
        }
      __syncthreads();
      if (tid < 12) {
        const int c = tid >> 2, bb = tid & 3;
        float v = sRed[c*4+bb] + sRed[12 + c*4+bb] + sRed[24 + c*4+bb] + sRed[36 + c*4+bb];
        const int gc = g*3 + c;
        tgbuf[par*3072 + bb*768 + gc] = f2b(geluf(v + b1[gc]));
      }
      __threadfence();
      __syncthreads();
      if (tid == 0)
        __hip_atomic_store(fP2 + g, t + 1, __ATOMIC_RELAXED, __HIP_MEMORY_SCOPE_AGENT);
    }

    // ================= P3: x2 EMA, cb, u slice =================
    {
      {
        int* p = fP2 + tid;
        while (__hip_atomic_load(p, __ATOMIC_RELAXED, __HIP_MEMORY_SCOPE_AGENT) < t + 1)
          __builtin_amdgcn_s_sleep(1);
      }
      __syncthreads();
      __threadfence();
      const int base = par*3072 + wv*768 + lane*12;
      float tv[12], xv2[12];
      {
        const uint2* p = (const uint2*)(tgbuf + base);
        unp4(p[0], tv); unp4(p[1], tv+4); unp4(p[2], tv+8);
      }
      const int xb = wv*768 + lane*12;
      float ssqT = 0.f, ssqX = 0.f;
      #pragma unroll
      for (int i = 0; i < 12; ++i) {
        float xx = sX2[xb + i];
        const float tt = tv[i];
        #pragma unroll
        for (int rr = 0; rr < 10; ++rr) xx = 0.5f*xx + 0.5f*tt;
        sX2[xb + i] = xx; xv2[i] = xx;
        ssqT += tt*tt; ssqX += xx*xx;
      }
      ssqT = wsum(ssqT); ssqX = wsum(ssqX);
      const float invT = 1.0f / fmaxf(sqrtf(ssqT), 1e-12f);
      const float invX = 1.0f / fmaxf(sqrtf(ssqX), 1e-12f);
      #pragma unroll
      for (int i = 0; i < 12; ++i) sX[xb + i] = 0.5f*(tv[i]*invT + xv2[i]*invX);
      __syncthreads();
      const int ks = lane, isub = wv;
      float acc[3][4] = {};
      #pragma unroll
      for (int ip = 0; ip < 3; ++ip) {
        const int k = ks + 64*(isub + 4*ip);
        float xv[4];
        #pragma unroll
        for (int bb = 0; bb < 4; ++bb) xv[bb] = sX[bb*768 + k];
        #pragma unroll
        for (int c = 0; c < 3; ++c) {
          const float w = sW1[c*768 + k];
          acc[c][0] += w*xv[0]; acc[c][1] += w*xv[1]; acc[c][2] += w*xv[2]; acc[c][3] += w*xv[3];
        }
      }
      #pragma unroll
      for (int c = 0; c < 3; ++c)
        #pragma unroll
        for (int bb = 0; bb < 4; ++bb) {
          const float v = wsum(acc[c][bb]);
          if (lane == 0) sRed[isub*12 + c*4 + bb] = v;
        }
      __syncthreads();
      if (tid < 12) {
        const int c = tid >> 2, bb = tid & 3;
        float v = sRed[c*4+bb] + sRed[12 + c*4+bb] + sRed[24 + c*4+bb] + sRed[36 + c*4+bb];
        const int gc = g*3 + c;
        ubuf[par*3072 + bb*768 + gc] = f2b(geluf(v + c1[gc]));
      }
      __threadfence();
      __syncthreads();
      if (tid == 0)
        __hip_atomic_store(fP3 + g, t + 1, __ATOMIC_RELAXED, __HIP_MEMORY_SCOPE_AGENT);
    }

    // ================= P4: cf slice, gv slice =================
    {
      {
        int* p = fP3 + tid;
        while (__hip_atomic_load(p, __ATOMIC_RELAXED, __HIP_MEMORY_SCOPE_AGENT) < t + 1)
          __builtin_amdgcn_s_sleep(1);
      }
      __syncthreads();
      __threadfence();
      const int base = par*3072 + wv*768 + lane*12;
      float uv[12];
      {
        const uint2* p = (const uint2*)(ubuf + base);
        unp4(p[0], uv); unp4(p[1], uv+4); unp4(p[2], uv+8);
      }
      const int xb = wv*768 + lane*12;
      #pragma unroll
      for (int i = 0; i < 12; ++i) sX[xb + i] = uv[i];
      __syncthreads();
      const int ks = lane, isub = wv;
      float acc[6][4] = {};
      #pragma unroll
      for (int ip = 0; ip < 3; ++ip) {
        const int k = ks + 64*(isub + 4*ip);
        float xv[4];
        #pragma unroll
        for (int bb = 0; bb < 4; ++bb) xv[bb] = sX[bb*768 + k];
        #pragma unroll
        for (int c = 0; c < 6; ++c) {
          const float w = (c < 3) ? sW2[c*768 + k] : sW2G[(c-3)*768 + k];
          acc[c][0] += w*xv[0]; acc[c][1] += w*xv[1]; acc[c][2] += w*xv[2]; acc[c][3] += w*xv[3];
        }
      }
      #pragma unroll
      for (int c = 0; c < 6; ++c)
        #pragma unroll
        for (int bb = 0; bb < 4; ++bb) {
          const float v = wsum(acc[c][bb]);
          if (lane == 0) sRed[isub*24 + c*4 + bb] = v;
        }
      __syncthreads();
      if (tid < 24) {
        const int c = tid >> 2, bb = tid & 3;
        float v = sRed[c*4+bb] + sRed[24 + c*4+bb] + sRed[48 + c*4+bb] + sRed[72 + c*4+bb];
        if (c < 3) {
          const int gc = g*3 + c;
          cfbuf[par*3072 + bb*768 + gc] = f2b(v + c2[gc]);
        } else {
          const int gc = g*3 + (c - 3);
          const float gv = v + embWg[(size_t)(bb*256 + t)*768 + gc] + gbias[gc];
          gvbuf[par*3072 + bb*768 + gc] = f2b(gv);
        }
      }
      __threadfence();
      __syncthreads();
      if (tid == 0)
        __hip_atomic_store(fP4 + g, t + 1, __ATOMIC_RELAXED, __HIP_MEMORY_SCOPE_AGENT);
    }
  }
}

// ---------------------------------------------------------------------------
// host
// ---------------------------------------------------------------------------
static void launch_gemm(const float* A, const void* B, float* C, const float* bias,
                        int M, int N, int bmode, hipStream_t st)
{
  const int ntiles = (N + 63) / 64;
  const int q = ntiles / 8, r = ntiles % 8;
  const int mtiles = M / 64;
  const int smax = (q + (r ? 1 : 0)) * mtiles;
  dim3 grid(8, smax);
  if (bmode == 0) gemm_kernel<0><<<grid, 256, 0, st>>>(A, B, C, bias, M, N, q, r);
  else            gemm_kernel<1><<<grid, 256, 0, st>>>(A, B, C, bias, M, N, q, r);
}

extern "C" void kernel_launch(void* const* d_in, const int* in_sizes, int n_in,
                              void* d_out, int out_size, void* d_ws, size_t ws_size,
                              hipStream_t stream)
{
  const int*   tok   = (const int*)d_in[0];
  const float* emb   = (const float*)d_in[1];
  const float* V0    = (const float*)d_in[2];
  const float* b0    = (const float*)d_in[3];
  const float* V1    = (const float*)d_in[4];
  const float* b1    = (const float*)d_in[5];
  const float* W1    = (const float*)d_in[6];
  const float* c1    = (const float*)d_in[7];
  const float* W2    = (const float*)d_in[8];
  const float* c2    = (const float*)d_in[9];
  const float* Wg    = (const float*)d_in[10];
  const float* bg    = (const float*)d_in[11];
  const float* Wt    = (const float*)d_in[12];
  const float* gamma = (const float*)d_in[13];
  const float* beta  = (const float*)d_in[14];
  const float* Wl    = (const float*)d_in[15];
  const float* Rw    = (const float*)d_in[16];

  float* outf = (float*)d_out;
  // scratch carved from d_out (all fully consumed before the final GEMM
  // overwrites d_out). float-slot offsets:
  float* emb_all = outf + 0;                    //  786432
  float* RV0     = outf + 786432;               // 2359296
  float* RWt     = outf + 3145728;              //  589824
  float* W2G     = outf + 3735552;              //  589824
  float* embV0   = outf + 4325376;              // 3145728
  float* embWg   = outf + 7471104;              //  786432
  float* gbias   = outf + 8257536;              //    1024
  unsigned short* V0T  = (unsigned short*)(outf + 8258560);   // 2359296 el
  unsigned short* WtT  = (unsigned short*)(outf + 9438208);   //  589824 el
  unsigned short* WgTT = (unsigned short*)(outf + 9733120);   //  589824 el
  unsigned short* WgBT = (unsigned short*)(outf + 10028032);  //  589824 el
  unsigned short* a1buf = (unsigned short*)(outf + 10322944); // 2*4*3072
  unsigned short* tfbuf = (unsigned short*)(outf + 10335232); // 2*4*768
  unsigned short* tgbuf = (unsigned short*)(outf + 10338304);
  unsigned short* ubuf  = (unsigned short*)(outf + 10341376);
  unsigned short* cfbuf = (unsigned short*)(outf + 10344448);
  unsigned short* gvbuf = (unsigned short*)(outf + 10347520);
  int*            flg   = (int*)(outf + 10350592);            // 1024 ints

  // workspace: h_all (must survive into the final GEMM) + optional WlT
  float* h_all = (float*)d_ws;                                // 786432 f32
  unsigned short* WlT = (unsigned short*)((char*)d_ws + 786432*4);
  const bool bigws = ws_size >= (size_t)(786432*4) + (size_t)38597376*2 + 256;

  hipMemsetAsync(flg, 0, 1024 * sizeof(int), stream);

  // transposed bf16 copies of GEMM B operands
  transpose_f2b<<<dim3(96, 24),   256, 0, stream>>>(V0, V0T, 3072, 0);
  transpose_f2b<<<dim3(24, 24),   256, 0, stream>>>(Wt, WtT, 768, 0);
  transpose_f2b<<<dim3(24, 24),   256, 0, stream>>>(Wg, WgTT, 768, 0);
  transpose_f2b<<<dim3(24, 24),   256, 0, stream>>>(Wg, WgBT, 768, 768);
  if (bigws)
    transpose_f2b<<<dim3(1572, 24), 256, 0, stream>>>(Wl, WlT, 50257, 0);

  embed_kernel<<<1024, 256, 0, stream>>>(tok, emb, emb_all);
  gbias_kernel<<<3, 256, 0, stream>>>(c2, Wg, gbias);

  // fused-weight + per-token precompute GEMMs (bf16 MFMA, fp32 out)
  launch_gemm(Rw,      V0T,  RV0,   nullptr, 768,  3072, 0, stream);
  launch_gemm(Rw,      WtT,  RWt,   nullptr, 768,  768,  0, stream);
  launch_gemm(W2,      WgBT, W2G,   nullptr, 768,  768,  0, stream);
  launch_gemm(emb_all, V0T,  embV0, b0,      1024, 3072, 0, stream);
  launch_gemm(emb_all, WgTT, embWg, bg,      1024, 768,  0, stream);

  // the sequential part
  recur_kernel<<<256, 256, 0, stream>>>(
      RV0, RWt, W1, W2, W2G, V1, embV0, embWg, gbias, emb_all,
      b1, c1, c2, gamma, beta, h_all,
      a1buf, tfbuf, tgbuf, ubuf, cfbuf, gvbuf, flg);

  // deferred lm_head: logits[b*256+t][v] = h_all @ Wl
  if (bigws) launch_gemm(h_all, WlT, outf, nullptr, 1024, 50257, 0, stream);
  else       launch_gemm(h_all, Wl,  outf, nullptr, 1024, 50257, 1, stream);
}

// Round 2
// 12464.194 us; speedup vs baseline: 3.2635x; 3.2635x over previous
//
#include <hip/hip_runtime.h>

// ============================================================================
// AgnisV5: sequential recurrence (4-phase persistent kernel, weights in LDS)
//          + deferred batched lm_head GEMM (bf16 MFMA).
//
// Round-2 change: sync protocol. No __threadfence (= buffer_wbl2/inv L2 flush,
// which cost 38us/phase + 252MB HBM refetch). Inter-WG payloads now travel as
// RELAXED AGENT-SCOPE 64-bit atomics (sc1: bypass non-coherent per-XCD L2,
// served by the memory-side Infinity Cache = the coherence point). Barrier =
// payload st64.sc1 -> s_waitcnt vmcnt(0) -> __syncthreads -> one agent-scope
// fetch_add on a per-phase counter; consumers poll with tid==0 only.
// ============================================================================

typedef __attribute__((ext_vector_type(8))) short short8;
typedef __attribute__((ext_vector_type(4))) float f32x4;
typedef unsigned long long u64;

__device__ __forceinline__ unsigned short f2b(float f){
  unsigned int u = __builtin_bit_cast(unsigned int, f);
  u += 0x7fffu + ((u >> 16) & 1u);
  return (unsigned short)(u >> 16);
}
__device__ __forceinline__ float b2f(unsigned short v){
  return __builtin_bit_cast(float, ((unsigned int)v) << 16);
}
__device__ __forceinline__ float geluf(float x){
  return 0.5f * x * (1.0f + erff(x * 0.70710678118654752440f));
}
__device__ __forceinline__ float wsum(float v){
  #pragma unroll
  for (int o = 32; o; o >>= 1) v += __shfl_xor(v, o, 64);
  return v;
}
__device__ __forceinline__ u64 pk4(float a, float b, float c, float d){
  return (u64)f2b(a) | ((u64)f2b(b) << 16) | ((u64)f2b(c) << 32) | ((u64)f2b(d) << 48);
}
__device__ __forceinline__ void up4(u64 v, float* o){
  o[0] = b2f((unsigned short)(v));
  o[1] = b2f((unsigned short)(v >> 16));
  o[2] = b2f((unsigned short)(v >> 32));
  o[3] = b2f((unsigned short)(v >> 48));
}
// agent-scope (sc1, L2-bypass, IF$-coherent) accessors
__device__ __forceinline__ void st64(u64* p, u64 v){
  __hip_atomic_store(p, v, __ATOMIC_RELAXED, __HIP_MEMORY_SCOPE_AGENT);
}
__device__ __forceinline__ u64 ld64(const u64* p){
  return __hip_atomic_load(p, __ATOMIC_RELAXED, __HIP_MEMORY_SCOPE_AGENT);
}
__device__ __forceinline__ int ldcnt(const int* p){
  return __hip_atomic_load(p, __ATOMIC_RELAXED, __HIP_MEMORY_SCOPE_AGENT);
}

// ---------------------------------------------------------------------------
// transpose + f32->bf16 : src [768, N] (rows offset by rowoff) -> dst [N, 768]
// ---------------------------------------------------------------------------
__global__ __launch_bounds__(256) void transpose_f2b(
    const float* __restrict__ src, unsigned short* __restrict__ dst,
    int N, int rowoff)
{
  __shared__ unsigned short tile[32][33];
  const int nb = blockIdx.x * 32, kb = blockIdx.y * 32;
  const int tx = threadIdx.x & 31, ty = threadIdx.x >> 5;
  #pragma unroll
  for (int i = 0; i < 4; ++i) {
    int k = kb + ty + 8*i, n = nb + tx;
    unsigned short v = 0;
    if (n < N) v = f2b(src[(size_t)(rowoff + k)*N + n]);
    tile[ty + 8*i][tx] = v;
  }
  __syncthreads();
  #pragma unroll
  for (int i = 0; i < 4; ++i) {
    int n = nb + ty + 8*i;
    if (n < N) dst[(size_t)n*768 + kb + tx] = tile[tx][ty + 8*i];
  }
}

// ---------------------------------------------------------------------------
// embedding gather + L2 normalize : emb_all[b*256+t][768]
// ---------------------------------------------------------------------------
__global__ __launch_bounds__(256) void embed_kernel(
    const int* __restrict__ tok, const float* __restrict__ emb,
    float* __restrict__ emb_all)
{
  const int row = blockIdx.x, tid = threadIdx.x;
  const int id = tok[row];
  const float* e = emb + (size_t)id * 768;
  float v0 = e[tid], v1 = e[tid+256], v2 = e[tid+512];
  float ssq = wsum(v0*v0 + v1*v1 + v2*v2);
  __shared__ float red[4];
  if ((tid & 63) == 0) red[tid >> 6] = ssq;
  __syncthreads();
  float inv = 1.0f / fmaxf(sqrtf(red[0]+red[1]+red[2]+red[3]), 1e-12f);
  float* o = emb_all + (size_t)row * 768;
  o[tid] = v0*inv; o[tid+256] = v1*inv; o[tid+512] = v2*inv;
}

// gbias[c] = sum_k c2[k] * Wg[768+k][c]
__global__ void gbias_kernel(const float* __restrict__ c2,
                             const float* __restrict__ Wg,
                             float* __restrict__ gbias)
{
  int c = blockIdx.x * 256 + threadIdx.x;
  if (c >= 768) return;
  float s = 0.f;
  for (int k = 0; k < 768; ++k) s += c2[k] * Wg[(size_t)(768 + k)*768 + c];
  gbias[c] = s;
}

// ---------------------------------------------------------------------------
// GEMM: C[M,N] = A[M,768](f32, bf16-cast) @ B + bias
//   BMODE 0: B = BT bf16 [N,768] (transposed)   BMODE 1: B = f32 [768,N]
// 64x64 tile/WG, mfma_f32_16x16x32_bf16, XCD-partitioned grid over N-tiles.
// ---------------------------------------------------------------------------
template<int BMODE>
__global__ __launch_bounds__(256) void gemm_kernel(
    const float* __restrict__ A, const void* __restrict__ Bp,
    float* __restrict__ C, const float* __restrict__ bias,
    int M, int N, int q, int r)
{
  const int x = blockIdx.x;             // xcd slot (blockIdx round-robins XCDs)
  const int s = blockIdx.y;
  const int mtiles = M >> 6;
  const int cnt_x = q + (x < r ? 1 : 0);
  if (s >= cnt_x * mtiles) return;
  const int off_x = x*q + (x < r ? x : r);
  const int nt = off_x + s / mtiles;
  const int mt = s % mtiles;
  const int m0 = mt << 6, n0 = nt << 6;
  const int w = threadIdx.x >> 6, l = threadIdx.x & 63;
  const int lrow = l & 15, lk8 = (l >> 4) << 3;
  const int arow = m0 + w*16 + lrow;
  f32x4 acc[4] = {f32x4{0,0,0,0}, f32x4{0,0,0,0}, f32x4{0,0,0,0}, f32x4{0,0,0,0}};
  const unsigned short* BT = (const unsigned short*)Bp;
  const float* Bf = (const float*)Bp;

  for (int kk = 0; kk < 768; kk += 32) {
    const float4* ap = (const float4*)(A + (size_t)arow*768 + kk + lk8);
    float4 a0 = ap[0], a1 = ap[1];
    short8 af;
    af[0]=(short)f2b(a0.x); af[1]=(short)f2b(a0.y); af[2]=(short)f2b(a0.z); af[3]=(short)f2b(a0.w);
    af[4]=(short)f2b(a1.x); af[5]=(short)f2b(a1.y); af[6]=(short)f2b(a1.z); af[7]=(short)f2b(a1.w);
    #pragma unroll
    for (int ss = 0; ss < 4; ++ss) {
      const int col = n0 + ss*16 + lrow;
      short8 bf;
      if (BMODE == 0) {
        if (col < N) {
          uint4 raw = *(const uint4*)(BT + (size_t)col*768 + kk + lk8);
          bf = __builtin_bit_cast(short8, raw);
        } else {
          bf = short8{0,0,0,0,0,0,0,0};
        }
      } else {
        #pragma unroll
        for (int j = 0; j < 8; ++j) {
          float v = (col < N) ? Bf[(size_t)(kk + lk8 + j)*N + col] : 0.f;
          bf[j] = (short)f2b(v);
        }
      }
      acc[ss] = __builtin_amdgcn_mfma_f32_16x16x32_bf16(af, bf, acc[ss], 0, 0, 0);
    }
  }
  const int rbase = m0 + w*16 + ((l >> 4) << 2);
  #pragma unroll
  for (int ss = 0; ss < 4; ++ss) {
    const int col = n0 + ss*16 + lrow;
    if (col < N) {
      const float badd = bias ? bias[col] : 0.f;
      #pragma unroll
      for (int rr = 0; rr < 4; ++rr)
        C[(size_t)(rbase + rr)*N + col] = acc[ss][rr] + badd;
    }
  }
}

// ---------------------------------------------------------------------------
// Persistent recurrent kernel: 256 WGs (1/CU), 256 threads.
// WG g owns cols [g*12,+12) of RV0 and [g*3,+3) of V1/W1/W2/W2G/RWt in LDS.
// Sync: per-phase monotone counters (agent-scope atomics at IF$), payloads
// via packed-bf16 u64 agent-scope atomics. No threadfence anywhere.
// Payload layouts:
//   a1_64: [par][4 bb][768]  u64 (4 bf16 cols each)
//   tf/tg/u/cf/gv_64: [par][256 g][4 bb] u64 ({c0,c1,c2,pad})
// ---------------------------------------------------------------------------
__global__ __launch_bounds__(256) void recur_kernel(
    const float* __restrict__ RV0, const float* __restrict__ RWt,
    const float* __restrict__ W1,  const float* __restrict__ W2,
    const float* __restrict__ W2G, const float* __restrict__ V1,
    const float* __restrict__ embV0, const float* __restrict__ embWg,
    const float* __restrict__ gbias, const float* __restrict__ emb_all,
    const float* __restrict__ b1, const float* __restrict__ c1,
    const float* __restrict__ c2, const float* __restrict__ gam,
    const float* __restrict__ bet, float* __restrict__ h_all,
    u64* __restrict__ a1_64, u64* __restrict__ tf_64,
    u64* __restrict__ tg_64, u64* __restrict__ u_64,
    u64* __restrict__ cf_64, u64* __restrict__ gv_64,
    int* __restrict__ cnt)
{
  __shared__ float sRV0[12*768];        // 36864 B
  __shared__ float sV1[3*3072];         // 36864 B
  __shared__ float sW1[3*768];
  __shared__ float sW2[3*768];
  __shared__ float sW2G[3*768];
  __shared__ float sRWt[3*768];         // 4 x 9216 B
  __shared__ float sX[4*768];           // 12288 B (h / cb / u)
  __shared__ float sX2[4*768];          // 12288 B (x2 state, replicated)
  __shared__ u64   sA1_64[3072];        // 24576 B (a1 bf16 staged)
  __shared__ float sRed[256];           // 1024 B   -- total 160768 B
  unsigned short* sA1 = (unsigned short*)sA1_64;

  const int g = blockIdx.x, tid = threadIdx.x;
  const int wv = tid >> 6, lane = tid & 63;

  // ---- load weight slices into LDS ----
  for (int i = tid; i < 12*768; i += 256) {
    int k = i / 12, c = i - k*12;
    sRV0[c*768 + k] = RV0[(size_t)k*3072 + g*12 + c];
  }
  for (int i = tid; i < 3*3072; i += 256) {
    int k = i / 3, c = i - k*3;
    sV1[c*3072 + k] = V1[(size_t)k*768 + g*3 + c];
  }
  for (int i = tid; i < 3*768; i += 256) {
    int k = i / 3, c = i - k*3;
    const int gc = g*3 + c;
    sW1[c*768 + k]  = W1[(size_t)k*768 + gc];
    sW2[c*768 + k]  = W2[(size_t)k*768 + gc];
    sW2G[c*768 + k] = W2G[(size_t)k*768 + gc];
    sRWt[c*768 + k] = RWt[(size_t)k*768 + gc];
  }
  for (int i = tid; i < 4*768; i += 256) sX2[i] = 0.f;
  __syncthreads();

  int* cP1 = cnt + 0;
  int* cP2 = cnt + 64;
  int* cP3 = cnt + 128;
  int* cP4 = cnt + 192;

  for (int t = 0; t <= 256; ++t) {
    // ================= h_{t-1} (redundant in every WG) =================
    if (t == 0) {
      for (int i = tid; i < 4*768; i += 256) sX[i] = 0.f;
    } else {
      if (tid == 0) {
        while (ldcnt(cP4) < 256*t) __builtin_amdgcn_s_sleep(1);
      }
      __syncthreads();
      const int par = (t - 1) & 1;
      const int wbase = par*1024 + (lane*4)*4 + wv;   // + q*4 walks the 4 WGs
      float cfv[12], gvv[12], tfv[12], emv[12], pre[12];
      {
        float tmp[4];
        #pragma unroll
        for (int qq = 0; qq < 4; ++qq) {
          up4(ld64(cf_64 + wbase + qq*4), tmp);
          cfv[qq*3+0]=tmp[0]; cfv[qq*3+1]=tmp[1]; cfv[qq*3+2]=tmp[2];
        }
        #pragma unroll
        for (int qq = 0; qq < 4; ++qq) {
          up4(ld64(gv_64 + wbase + qq*4), tmp);
          gvv[qq*3+0]=tmp[0]; gvv[qq*3+1]=tmp[1]; gvv[qq*3+2]=tmp[2];
        }
        #pragma unroll
        for (int qq = 0; qq < 4; ++qq) {
          up4(ld64(tf_64 + wbase + qq*4), tmp);
          tfv[qq*3+0]=tmp[0]; tfv[qq*3+1]=tmp[1]; tfv[qq*3+2]=tmp[2];
        }
        const float4* q4 = (const float4*)(emb_all + (size_t)(wv*256 + t - 1)*768 + lane*12);
        float4 e0 = q4[0], e1 = q4[1], e2 = q4[2];
        emv[0]=e0.x; emv[1]=e0.y; emv[2]=e0.z; emv[3]=e0.w;
        emv[4]=e1.x; emv[5]=e1.y; emv[6]=e1.z; emv[7]=e1.w;
        emv[8]=e2.x; emv[9]=e2.y; emv[10]=e2.z; emv[11]=e2.w;
      }
      float s1 = 0.f;
      #pragma unroll
      for (int i = 0; i < 12; ++i) {
        const float gg = 1.0f / (1.0f + expf(-gvv[i]));
        pre[i] = gg*(cfv[i] + 0.4f*tfv[i]) + (1.0f - gg)*emv[i];
        s1 += pre[i];
      }
      s1 = wsum(s1);
      const float mean = s1 * (1.0f/768.0f);
      float s2 = 0.f;
      #pragma unroll
      for (int i = 0; i < 12; ++i) { const float d = pre[i] - mean; s2 += d*d; }
      s2 = wsum(s2);
      const float rstd = 1.0f / sqrtf(s2*(1.0f/768.0f) + 1e-5f);
      const int k0 = lane*12;
      float hv[12];
      #pragma unroll
      for (int i = 0; i < 12; ++i) {
        hv[i] = (pre[i] - mean)*rstd*gam[k0+i] + bet[k0+i];
        sX[wv*768 + k0 + i] = hv[i];
      }
      if (g == 0) {
        float* hp = h_all + (size_t)(wv*256 + t - 1)*768 + k0;
        #pragma unroll
        for (int i = 0; i < 12; ++i) hp[i] = hv[i];
      }
    }
    __syncthreads();
    if (t == 256) break;
    const int par = t & 1;

    // ================= P1: a1 slice, tf slice =================
    {
      const int cg = tid >> 6, ks = tid & 63;
      float acc[4][4] = {};
      for (int i = 0; i < 12; ++i) {
        const int k = ks + 64*i;
        const float x0 = sX[k], x1 = sX[768+k], x2v = sX[1536+k], x3 = sX[2304+k];
        #pragma unroll
        for (int j = 0; j < 4; ++j) {
          float w;
          if (cg < 3) w = sRV0[(cg*4 + j)*768 + k];
          else        w = (j < 3) ? sRWt[j*768 + k] : 0.f;
          acc[j][0] += w*x0; acc[j][1] += w*x1; acc[j][2] += w*x2v; acc[j][3] += w*x3;
        }
      }
      #pragma unroll
      for (int j = 0; j < 4; ++j)
        #pragma unroll
        for (int bb = 0; bb < 4; ++bb) {
          const float v = wsum(acc[j][bb]);
          if (lane == 0) sRed[cg*16 + j*4 + bb] = v;
        }
      __syncthreads();
      if (tid < 16) {
        if (tid < 12) {
          const int bb = tid & 3, i = tid >> 2;      // i = 0..2 (u64 within bb)
          float v[4];
          #pragma unroll
          for (int j = 0; j < 4; ++j) {
            const int c = i*4 + j;
            const float raw = sRed[i*16 + j*4 + bb];
            v[j] = geluf(embV0[(size_t)(bb*256 + t)*3072 + g*12 + c] + 0.4f*raw);
          }
          st64(a1_64 + par*3072 + bb*768 + g*3 + i, pk4(v[0],v[1],v[2],v[3]));
        } else {
          const int bb = tid - 12;
          st64(tf_64 + par*1024 + g*4 + bb,
               pk4(sRed[48+bb], sRed[48+4+bb], sRed[48+8+bb], 0.f));
        }
      }
      asm volatile("s_waitcnt vmcnt(0)" ::: "memory");
      __syncthreads();
      if (tid == 0)
        __hip_atomic_fetch_add(cP1, 1, __ATOMIC_RELAXED, __HIP_MEMORY_SCOPE_AGENT);
    }

    // ================= P2: target slice =================
    {
      if (tid == 0) {
        while (ldcnt(cP1) < 256*(t+1)) __builtin_amdgcn_s_sleep(1);
      }
      __syncthreads();
      for (int i = tid; i < 3072; i += 256)
        sA1_64[i] = ld64(a1_64 + par*3072 + i);
      __syncthreads();
      const int ks = lane, isub = wv;
      float acc[3][4] = {};
      for (int ip = 0; ip < 12; ++ip) {
        const int k = ks + 64*(isub + 4*ip);
        float xv[4];
        #pragma unroll
        for (int bb = 0; bb < 4; ++bb) xv[bb] = b2f(sA1[bb*3072 + k]);
        #pragma unroll
        for (int c = 0; c < 3; ++c) {
          const float w = sV1[c*3072 + k];
          acc[c][0] += w*xv[0]; acc[c][1] += w*xv[1]; acc[c][2] += w*xv[2]; acc[c][3] += w*xv[3];
        }
      }
      #pragma unroll
      for (int c = 0; c < 3; ++c)
        #pragma unroll
        for (int bb = 0; bb < 4; ++bb) {
          const float v = wsum(acc[c][bb]);
          if (lane == 0) sRed[isub*12 + c*4 + bb] = v;
        }
      __syncthreads();
      if (tid < 4) {
        const int bb = tid;
        float v[3];
        #pragma unroll
        for (int c = 0; c < 3; ++c) {
          float s = sRed[c*4+bb] + sRed[12 + c*4+bb] + sRed[24 + c*4+bb] + sRed[36 + c*4+bb];
          v[c] = geluf(s + b1[g*3 + c]);
        }
        st64(tg_64 + par*1024 + g*4 + bb, pk4(v[0], v[1], v[2], 0.f));
      }
      asm volatile("s_waitcnt vmcnt(0)" ::: "memory");
      __syncthreads();
      if (tid == 0)
        __hip_atomic_fetch_add(cP2, 1, __ATOMIC_RELAXED, __HIP_MEMORY_SCOPE_AGENT);
    }

    // ================= P3: x2 EMA, cb, u slice =================
    {
      if (tid == 0) {
        while (ldcnt(cP2) < 256*(t+1)) __builtin_amdgcn_s_sleep(1);
      }
      __syncthreads();
      const int wbase = par*1024 + (lane*4)*4 + wv;
      float tv[12];
      {
        float tmp[4];
        #pragma unroll
        for (int qq = 0; qq < 4; ++qq) {
          up4(ld64(tg_64 + wbase + qq*4), tmp);
          tv[qq*3+0]=tmp[0]; tv[qq*3+1]=tmp[1]; tv[qq*3+2]=tmp[2];
        }
      }
      const int xb = wv*768 + lane*12;
      float xv2[12];
      float ssqT = 0.f, ssqX = 0.f;
      #pragma unroll
      for (int i = 0; i < 12; ++i) {
        float xx = sX2[xb + i];
        const float tt = tv[i];
        #pragma unroll
        for (int rr = 0; rr < 10; ++rr) xx = 0.5f*xx + 0.5f*tt;
        sX2[xb + i] = xx; xv2[i] = xx;
        ssqT += tt*tt; ssqX += xx*xx;
      }
      ssqT = wsum(ssqT); ssqX = wsum(ssqX);
      const float invT = 1.0f / fmaxf(sqrtf(ssqT), 1e-12f);
      const float invX = 1.0f / fmaxf(sqrtf(ssqX), 1e-12f);
      #pragma unroll
      for (int i = 0; i < 12; ++i) sX[xb + i] = 0.5f*(tv[i]*invT + xv2[i]*invX);
      __syncthreads();
      const int ks = lane, isub = wv;
      float acc[3][4] = {};
      #pragma unroll
      for (int ip = 0; ip < 3; ++ip) {
        const int k = ks + 64*(isub + 4*ip);
        float xv[4];
        #pragma unroll
        for (int bb = 0; bb < 4; ++bb) xv[bb] = sX[bb*768 + k];
        #pragma unroll
        for (int c = 0; c < 3; ++c) {
          const float w = sW1[c*768 + k];
          acc[c][0] += w*xv[0]; acc[c][1] += w*xv[1]; acc[c][2] += w*xv[2]; acc[c][3] += w*xv[3];
        }
      }
      #pragma unroll
      for (int c = 0; c < 3; ++c)
        #pragma unroll
        for (int bb = 0; bb < 4; ++bb) {
          const float v = wsum(acc[c][bb]);
          if (lane == 0) sRed[isub*12 + c*4 + bb] = v;
        }
      __syncthreads();
      if (tid < 4) {
        const int bb = tid;
        float v[3];
        #pragma unroll
        for (int c = 0; c < 3; ++c) {
          float s = sRed[c*4+bb] + sRed[12 + c*4+bb] + sRed[24 + c*4+bb] + sRed[36 + c*4+bb];
          v[c] = geluf(s + c1[g*3 + c]);
        }
        st64(u_64 + par*1024 + g*4 + bb, pk4(v[0], v[1], v[2], 0.f));
      }
      asm volatile("s_waitcnt vmcnt(0)" ::: "memory");
      __syncthreads();
      if (tid == 0)
        __hip_atomic_fetch_add(cP3, 1, __ATOMIC_RELAXED, __HIP_MEMORY_SCOPE_AGENT);
    }

    // ================= P4: cf slice, gv slice =================
    {
      if (tid == 0) {
        while (ldcnt(cP3) < 256*(t+1)) __builtin_amdgcn_s_sleep(1);
      }
      __syncthreads();
      const int wbase = par*1024 + (lane*4)*4 + wv;
      float uv[12];
      {
        float tmp[4];
        #pragma unroll
        for (int qq = 0; qq < 4; ++qq) {
          up4(ld64(u_64 + wbase + qq*4), tmp);
          uv[qq*3+0]=tmp[0]; uv[qq*3+1]=tmp[1]; uv[qq*3+2]=tmp[2];
        }
      }
      const int xb = wv*768 + lane*12;
      #pragma unroll
      for (int i = 0; i < 12; ++i) sX[xb + i] = uv[i];
      __syncthreads();
      const int ks = lane, isub = wv;
      float acc[6][4] = {};
      #pragma unroll
      for (int ip = 0; ip < 3; ++ip) {
        const int k = ks + 64*(isub + 4*ip);
        float xv[4];
        #pragma unroll
        for (int bb = 0; bb < 4; ++bb) xv[bb] = sX[bb*768 + k];
        #pragma unroll
        for (int c = 0; c < 6; ++c) {
          const float w = (c < 3) ? sW2[c*768 + k] : sW2G[(c-3)*768 + k];
          acc[c][0] += w*xv[0]; acc[c][1] += w*xv[1]; acc[c][2] += w*xv[2]; acc[c][3] += w*xv[3];
        }
      }
      #pragma unroll
      for (int c = 0; c < 6; ++c)
        #pragma unroll
        for (int bb = 0; bb < 4; ++bb) {
          const float v = wsum(acc[c][bb]);
          if (lane == 0) sRed[isub*24 + c*4 + bb] = v;
        }
      __syncthreads();
      if (tid < 4) {
        const int bb = tid;
        float vc[3], vg[3];
        #pragma unroll
        for (int c = 0; c < 3; ++c) {
          float s = sRed[c*4+bb] + sRed[24 + c*4+bb] + sRed[48 + c*4+bb] + sRed[72 + c*4+bb];
          vc[c] = s + c2[g*3 + c];
        }
        #pragma unroll
        for (int c = 0; c < 3; ++c) {
          const int cc = c + 3;
          float s = sRed[cc*4+bb] + sRed[24 + cc*4+bb] + sRed[48 + cc*4+bb] + sRed[72 + cc*4+bb];
          vg[c] = s + embWg[(size_t)(bb*256 + t)*768 + g*3 + c] + gbias[g*3 + c];
        }
        st64(cf_64 + par*1024 + g*4 + bb, pk4(vc[0], vc[1], vc[2], 0.f));
        st64(gv_64 + par*1024 + g*4 + bb, pk4(vg[0], vg[1], vg[2], 0.f));
      }
      asm volatile("s_waitcnt vmcnt(0)" ::: "memory");
      __syncthreads();
      if (tid == 0)
        __hip_atomic_fetch_add(cP4, 1, __ATOMIC_RELAXED, __HIP_MEMORY_SCOPE_AGENT);
    }
  }
}

// ---------------------------------------------------------------------------
// host
// ---------------------------------------------------------------------------
static void launch_gemm(const float* A, const void* B, float* C, const float* bias,
                        int M, int N, int bmode, hipStream_t st)
{
  const int ntiles = (N + 63) / 64;
  const int q = ntiles / 8, r = ntiles % 8;
  const int mtiles = M / 64;
  const int smax = (q + (r ? 1 : 0)) * mtiles;
  dim3 grid(8, smax);
  if (bmode == 0) gemm_kernel<0><<<grid, 256, 0, st>>>(A, B, C, bias, M, N, q, r);
  else            gemm_kernel<1><<<grid, 256, 0, st>>>(A, B, C, bias, M, N, q, r);
}

extern "C" void kernel_launch(void* const* d_in, const int* in_sizes, int n_in,
                              void* d_out, int out_size, void* d_ws, size_t ws_size,
                              hipStream_t stream)
{
  const int*   tok   = (const int*)d_in[0];
  const float* emb   = (const float*)d_in[1];
  const float* V0    = (const float*)d_in[2];
  const float* b0    = (const float*)d_in[3];
  const float* V1    = (const float*)d_in[4];
  const float* b1    = (const float*)d_in[5];
  const float* W1    = (const float*)d_in[6];
  const float* c1    = (const float*)d_in[7];
  const float* W2    = (const float*)d_in[8];
  const float* c2    = (const float*)d_in[9];
  const float* Wg    = (const float*)d_in[10];
  const float* bg    = (const float*)d_in[11];
  const float* Wt    = (const float*)d_in[12];
  const float* gamma = (const float*)d_in[13];
  const float* beta  = (const float*)d_in[14];
  const float* Wl    = (const float*)d_in[15];
  const float* Rw    = (const float*)d_in[16];

  float* outf = (float*)d_out;
  // scratch carved from d_out (all fully consumed before the final GEMM
  // overwrites d_out). float-slot offsets:
  float* emb_all = outf + 0;                    //  786432
  float* RV0     = outf + 786432;               // 2359296
  float* RWt     = outf + 3145728;              //  589824
  float* W2G     = outf + 3735552;               //  589824
  float* embV0   = outf + 4325376;              // 3145728
  float* embWg   = outf + 7471104;              //  786432
  float* gbias   = outf + 8257536;              //    1024
  unsigned short* V0T  = (unsigned short*)(outf + 8258560);   // 2359296 el
  unsigned short* WtT  = (unsigned short*)(outf + 9438208);   //  589824 el
  unsigned short* WgTT = (unsigned short*)(outf + 9733120);   //  589824 el
  unsigned short* WgBT = (unsigned short*)(outf + 10028032);  //  589824 el
  u64* a1_64 = (u64*)(outf + 10322944);   // 2*4*768 u64 = 12288 floats
  u64* tf_64 = (u64*)(outf + 10335232);   // 2*1024 u64  =  4096 floats
  u64* tg_64 = (u64*)(outf + 10339328);
  u64* u_64  = (u64*)(outf + 10343424);
  u64* cf_64 = (u64*)(outf + 10347520);
  u64* gv_64 = (u64*)(outf + 10351616);
  int* cnt   = (int*)(outf + 10355712);   // 4 counters, 256B apart

  // workspace: h_all (must survive into the final GEMM) + optional WlT
  float* h_all = (float*)d_ws;                                // 786432 f32
  unsigned short* WlT = (unsigned short*)((char*)d_ws + 786432*4);
  const bool bigws = ws_size >= (size_t)(786432*4) + (size_t)38597376*2 + 256;

  hipMemsetAsync(cnt, 0, 1024 * sizeof(int), stream);

  // transposed bf16 copies of GEMM B operands
  transpose_f2b<<<dim3(96, 24),   256, 0, stream>>>(V0, V0T, 3072, 0);
  transpose_f2b<<<dim3(24, 24),   256, 0, stream>>>(Wt, WtT, 768, 0);
  transpose_f2b<<<dim3(24, 24),   256, 0, stream>>>(Wg, WgTT, 768, 0);
  transpose_f2b<<<dim3(24, 24),   256, 0, stream>>>(Wg, WgBT, 768, 768);
  if (bigws)
    transpose_f2b<<<dim3(1572, 24), 256, 0, stream>>>(Wl, WlT, 50257, 0);

  embed_kernel<<<1024, 256, 0, stream>>>(tok, emb, emb_all);
  gbias_kernel<<<3, 256, 0, stream>>>(c2, Wg, gbias);

  // fused-weight + per-token precompute GEMMs (bf16 MFMA, fp32 out)
  launch_gemm(Rw,      V0T,  RV0,   nullptr, 768,  3072, 0, stream);
  launch_gemm(Rw,      WtT,  RWt,   nullptr, 768,  768,  0, stream);
  launch_gemm(W2,      WgBT, W2G,   nullptr, 768,  768,  0, stream);
  launch_gemm(emb_all, V0T,  embV0, b0,      1024, 3072, 0, stream);
  launch_gemm(emb_all, WgTT, embWg, bg,      1024, 768,  0, stream);

  // the sequential part
  recur_kernel<<<256, 256, 0, stream>>>(
      RV0, RWt, W1, W2, W2G, V1, embV0, embWg, gbias, emb_all,
      b1, c1, c2, gamma, beta, h_all,
      a1_64, tf_64, tg_64, u_64, cf_64, gv_64, cnt);

  // deferred lm_head: logits[b*256+t][v] = h_all @ Wl
  if (bigws) launch_gemm(h_all, WlT, outf, nullptr, 1024, 50257, 0, stream);
  else       launch_gemm(h_all, Wl,  outf, nullptr, 1024, 50257, 1, stream);
}

// Round 3
// 11034.254 us; speedup vs baseline: 3.6864x; 1.1296x over previous
//
#include <hip/hip_runtime.h>

// ============================================================================
// AgnisV5: sequential recurrence (4-phase persistent kernel, weights in LDS)
//          + deferred batched lm_head GEMM (bf16 MFMA).
//
// Round-3 change: ZERO-BARRIER DATAFLOW SYNC. Every inter-WG word is a u64
// atomic carrying 3 bf16 values + a 16-bit step tag (self-validating).
// Producers fire-and-forget st64.sc1; consumers poll exactly the words they
// consume until tags match the step. No counters, no fetch_add, no vmcnt, no
// fence: one fabric round trip per phase instead of three. Double-buffered by
// step parity; tag chain provides the WAR proof. Stale words from a previous
// (deterministic) replay can only match tags at the same step index, where
// the payload is bit-identical.
// ============================================================================

typedef __attribute__((ext_vector_type(8))) short short8;
typedef __attribute__((ext_vector_type(4))) float f32x4;
typedef unsigned long long u64;

__device__ __forceinline__ unsigned short f2b(float f){
  unsigned int u = __builtin_bit_cast(unsigned int, f);
  u += 0x7fffu + ((u >> 16) & 1u);
  return (unsigned short)(u >> 16);
}
__device__ __forceinline__ float b2f(unsigned short v){
  return __builtin_bit_cast(float, ((unsigned int)v) << 16);
}
__device__ __forceinline__ float geluf(float x){
  return 0.5f * x * (1.0f + erff(x * 0.70710678118654752440f));
}
__device__ __forceinline__ float wsum(float v){
  #pragma unroll
  for (int o = 32; o; o >>= 1) v += __shfl_xor(v, o, 64);
  return v;
}
// 3 bf16 + 16-bit tag packed in one atomic u64
__device__ __forceinline__ u64 pk3t(float a, float b, float c, unsigned short tag){
  return (u64)f2b(a) | ((u64)f2b(b) << 16) | ((u64)f2b(c) << 32) | ((u64)tag << 48);
}
__device__ __forceinline__ void st64(u64* p, u64 v){
  __hip_atomic_store(p, v, __ATOMIC_RELAXED, __HIP_MEMORY_SCOPE_AGENT);
}
__device__ __forceinline__ u64 ld64(const u64* p){
  return __hip_atomic_load(p, __ATOMIC_RELAXED, __HIP_MEMORY_SCOPE_AGENT);
}

// ---------------------------------------------------------------------------
// transpose + f32->bf16 : src [768, N] (rows offset by rowoff) -> dst [N, 768]
// ---------------------------------------------------------------------------
__global__ __launch_bounds__(256) void transpose_f2b(
    const float* __restrict__ src, unsigned short* __restrict__ dst,
    int N, int rowoff)
{
  __shared__ unsigned short tile[32][33];
  const int nb = blockIdx.x * 32, kb = blockIdx.y * 32;
  const int tx = threadIdx.x & 31, ty = threadIdx.x >> 5;
  #pragma unroll
  for (int i = 0; i < 4; ++i) {
    int k = kb + ty + 8*i, n = nb + tx;
    unsigned short v = 0;
    if (n < N) v = f2b(src[(size_t)(rowoff + k)*N + n]);
    tile[ty + 8*i][tx] = v;
  }
  __syncthreads();
  #pragma unroll
  for (int i = 0; i < 4; ++i) {
    int n = nb + ty + 8*i;
    if (n < N) dst[(size_t)n*768 + kb + tx] = tile[tx][ty + 8*i];
  }
}

// ---------------------------------------------------------------------------
// embedding gather + L2 normalize : emb_all[b*256+t][768]
// ---------------------------------------------------------------------------
__global__ __launch_bounds__(256) void embed_kernel(
    const int* __restrict__ tok, const float* __restrict__ emb,
    float* __restrict__ emb_all)
{
  const int row = blockIdx.x, tid = threadIdx.x;
  const int id = tok[row];
  const float* e = emb + (size_t)id * 768;
  float v0 = e[tid], v1 = e[tid+256], v2 = e[tid+512];
  float ssq = wsum(v0*v0 + v1*v1 + v2*v2);
  __shared__ float red[4];
  if ((tid & 63) == 0) red[tid >> 6] = ssq;
  __syncthreads();
  float inv = 1.0f / fmaxf(sqrtf(red[0]+red[1]+red[2]+red[3]), 1e-12f);
  float* o = emb_all + (size_t)row * 768;
  o[tid] = v0*inv; o[tid+256] = v1*inv; o[tid+512] = v2*inv;
}

// gbias[c] = sum_k c2[k] * Wg[768+k][c]
__global__ void gbias_kernel(const float* __restrict__ c2,
                             const float* __restrict__ Wg,
                             float* __restrict__ gbias)
{
  int c = blockIdx.x * 256 + threadIdx.x;
  if (c >= 768) return;
  float s = 0.f;
  for (int k = 0; k < 768; ++k) s += c2[k] * Wg[(size_t)(768 + k)*768 + c];
  gbias[c] = s;
}

// ---------------------------------------------------------------------------
// GEMM: C[M,N] = A[M,768](f32, bf16-cast) @ B + bias
//   BMODE 0: B = BT bf16 [N,768] (transposed)   BMODE 1: B = f32 [768,N]
// 64x64 tile/WG, mfma_f32_16x16x32_bf16, XCD-partitioned grid over N-tiles.
// ---------------------------------------------------------------------------
template<int BMODE>
__global__ __launch_bounds__(256) void gemm_kernel(
    const float* __restrict__ A, const void* __restrict__ Bp,
    float* __restrict__ C, const float* __restrict__ bias,
    int M, int N, int q, int r)
{
  const int x = blockIdx.x;             // xcd slot (blockIdx round-robins XCDs)
  const int s = blockIdx.y;
  const int mtiles = M >> 6;
  const int cnt_x = q + (x < r ? 1 : 0);
  if (s >= cnt_x * mtiles) return;
  const int off_x = x*q + (x < r ? x : r);
  const int nt = off_x + s / mtiles;
  const int mt = s % mtiles;
  const int m0 = mt << 6, n0 = nt << 6;
  const int w = threadIdx.x >> 6, l = threadIdx.x & 63;
  const int lrow = l & 15, lk8 = (l >> 4) << 3;
  const int arow = m0 + w*16 + lrow;
  f32x4 acc[4] = {f32x4{0,0,0,0}, f32x4{0,0,0,0}, f32x4{0,0,0,0}, f32x4{0,0,0,0}};
  const unsigned short* BT = (const unsigned short*)Bp;
  const float* Bf = (const float*)Bp;

  for (int kk = 0; kk < 768; kk += 32) {
    const float4* ap = (const float4*)(A + (size_t)arow*768 + kk + lk8);
    float4 a0 = ap[0], a1 = ap[1];
    short8 af;
    af[0]=(short)f2b(a0.x); af[1]=(short)f2b(a0.y); af[2]=(short)f2b(a0.z); af[3]=(short)f2b(a0.w);
    af[4]=(short)f2b(a1.x); af[5]=(short)f2b(a1.y); af[6]=(short)f2b(a1.z); af[7]=(short)f2b(a1.w);
    #pragma unroll
    for (int ss = 0; ss < 4; ++ss) {
      const int col = n0 + ss*16 + lrow;
      short8 bf;
      if (BMODE == 0) {
        if (col < N) {
          uint4 raw = *(const uint4*)(BT + (size_t)col*768 + kk + lk8);
          bf = __builtin_bit_cast(short8, raw);
        } else {
          bf = short8{0,0,0,0,0,0,0,0};
        }
      } else {
        #pragma unroll
        for (int j = 0; j < 8; ++j) {
          float v = (col < N) ? Bf[(size_t)(kk + lk8 + j)*N + col] : 0.f;
          bf[j] = (short)f2b(v);
        }
      }
      acc[ss] = __builtin_amdgcn_mfma_f32_16x16x32_bf16(af, bf, acc[ss], 0, 0, 0);
    }
  }
  const int rbase = m0 + w*16 + ((l >> 4) << 2);
  #pragma unroll
  for (int ss = 0; ss < 4; ++ss) {
    const int col = n0 + ss*16 + lrow;
    if (col < N) {
      const float badd = bias ? bias[col] : 0.f;
      #pragma unroll
      for (int rr = 0; rr < 4; ++rr)
        C[(size_t)(rbase + rr)*N + col] = acc[ss][rr] + badd;
    }
  }
}

// ---------------------------------------------------------------------------
// Persistent recurrent kernel: 256 WGs (1/CU), 256 threads.
// WG g owns cols [g*12,+12) of RV0 and [g*3,+3) of V1/W1/W2/W2G/RWt in LDS.
// Dataflow sync via tagged u64 words (see header comment).
// Layouts (all double-buffered by step parity):
//   a1_64: [par][4 bb][1024 words] ; word j = cols 3j..3j+2 (+tag)
//   tf/tg/u/cf/gv_64: [par][256 g][4 bb] ; word = 3 cols of WG g (+tag)
// Tags: production at step t carries tag (t+1).
// ---------------------------------------------------------------------------
__global__ __launch_bounds__(256) void recur_kernel(
    const float* __restrict__ RV0, const float* __restrict__ RWt,
    const float* __restrict__ W1,  const float* __restrict__ W2,
    const float* __restrict__ W2G, const float* __restrict__ V1,
    const float* __restrict__ embV0, const float* __restrict__ embWg,
    const float* __restrict__ gbias, const float* __restrict__ emb_all,
    const float* __restrict__ b1, const float* __restrict__ c1,
    const float* __restrict__ c2, const float* __restrict__ gam,
    const float* __restrict__ bet, float* __restrict__ h_all,
    u64* __restrict__ a1_64, u64* __restrict__ tf_64,
    u64* __restrict__ tg_64, u64* __restrict__ u_64,
    u64* __restrict__ cf_64, u64* __restrict__ gv_64)
{
  __shared__ float sRV0[12*768];        // 36864 B
  __shared__ float sV1[3*3072];         // 36864 B
  __shared__ float sW1[3*768];
  __shared__ float sW2[3*768];
  __shared__ float sW2G[3*768];
  __shared__ float sRWt[3*768];         // 4 x 9216 B
  __shared__ float sX[4*768];           // 12288 B (h / cb / u)
  __shared__ float sX2[4*768];          // 12288 B (x2 state, replicated)
  __shared__ unsigned short sA1[4*3072];// 24576 B (a1 bf16 staged)
  __shared__ float sRed[256];           // 1024 B   -- total 160768 B

  const int g = blockIdx.x, tid = threadIdx.x;
  const int wv = tid >> 6, lane = tid & 63;

  // ---- load weight slices into LDS ----
  for (int i = tid; i < 12*768; i += 256) {
    int k = i / 12, c = i - k*12;
    sRV0[c*768 + k] = RV0[(size_t)k*3072 + g*12 + c];
  }
  for (int i = tid; i < 3*3072; i += 256) {
    int k = i / 3, c = i - k*3;
    sV1[c*3072 + k] = V1[(size_t)k*768 + g*3 + c];
  }
  for (int i = tid; i < 3*768; i += 256) {
    int k = i / 3, c = i - k*3;
    const int gc = g*3 + c;
    sW1[c*768 + k]  = W1[(size_t)k*768 + gc];
    sW2[c*768 + k]  = W2[(size_t)k*768 + gc];
    sW2G[c*768 + k] = W2G[(size_t)k*768 + gc];
    sRWt[c*768 + k] = RWt[(size_t)k*768 + gc];
  }
  for (int i = tid; i < 4*768; i += 256) sX2[i] = 0.f;
  __syncthreads();

  for (int t = 0; t <= 256; ++t) {
    // ================= h_{t-1} (redundant in every WG) =================
    if (t == 0) {
      for (int i = tid; i < 4*768; i += 256) sX[i] = 0.f;
    } else {
      const int par = (t - 1) & 1;
      const int wb = par*1024 + lane*16 + wv;   // word of producer g=lane*4+qq
      // issue independent L2-path loads first (overlap with the poll)
      float emv[12];
      {
        const float4* q4 = (const float4*)(emb_all + (size_t)(wv*256 + t - 1)*768 + lane*12);
        float4 e0 = q4[0], e1 = q4[1], e2 = q4[2];
        emv[0]=e0.x; emv[1]=e0.y; emv[2]=e0.z; emv[3]=e0.w;
        emv[4]=e1.x; emv[5]=e1.y; emv[6]=e1.z; emv[7]=e1.w;
        emv[8]=e2.x; emv[9]=e2.y; emv[10]=e2.z; emv[11]=e2.w;
      }
      const int k0 = lane*12;
      float gamv[12], betv[12];
      #pragma unroll
      for (int i = 0; i < 12; ++i) { gamv[i] = gam[k0+i]; betv[i] = bet[k0+i]; }

      // dataflow poll: 12 tagged words (cf, gv, tf) from my 4 producers
      const unsigned short tagh = (unsigned short)t;
      u64 ww[12];
      bool ok;
      do {
        #pragma unroll
        for (int qq = 0; qq < 4; ++qq) {
          ww[qq]   = ld64(cf_64 + wb + qq*4);
          ww[4+qq] = ld64(gv_64 + wb + qq*4);
          ww[8+qq] = ld64(tf_64 + wb + qq*4);
        }
        ok = true;
        #pragma unroll
        for (int i = 0; i < 12; ++i) ok &= ((unsigned short)(ww[i] >> 48) == tagh);
      } while (__builtin_expect(!ok, 0));

      float cfv[12], gvv[12], tfv[12], pre[12];
      #pragma unroll
      for (int qq = 0; qq < 4; ++qq) {
        cfv[qq*3+0]=b2f((unsigned short)ww[qq]);
        cfv[qq*3+1]=b2f((unsigned short)(ww[qq]>>16));
        cfv[qq*3+2]=b2f((unsigned short)(ww[qq]>>32));
        gvv[qq*3+0]=b2f((unsigned short)ww[4+qq]);
        gvv[qq*3+1]=b2f((unsigned short)(ww[4+qq]>>16));
        gvv[qq*3+2]=b2f((unsigned short)(ww[4+qq]>>32));
        tfv[qq*3+0]=b2f((unsigned short)ww[8+qq]);
        tfv[qq*3+1]=b2f((unsigned short)(ww[8+qq]>>16));
        tfv[qq*3+2]=b2f((unsigned short)(ww[8+qq]>>32));
      }
      float s1 = 0.f;
      #pragma unroll
      for (int i = 0; i < 12; ++i) {
        const float gg = 1.0f / (1.0f + expf(-gvv[i]));
        pre[i] = gg*(cfv[i] + 0.4f*tfv[i]) + (1.0f - gg)*emv[i];
        s1 += pre[i];
      }
      s1 = wsum(s1);
      const float mean = s1 * (1.0f/768.0f);
      float s2 = 0.f;
      #pragma unroll
      for (int i = 0; i < 12; ++i) { const float d = pre[i] - mean; s2 += d*d; }
      s2 = wsum(s2);
      const float rstd = 1.0f / sqrtf(s2*(1.0f/768.0f) + 1e-5f);
      float hv[12];
      #pragma unroll
      for (int i = 0; i < 12; ++i) {
        hv[i] = (pre[i] - mean)*rstd*gamv[i] + betv[i];
        sX[wv*768 + k0 + i] = hv[i];
      }
      if (g == 0) {
        float* hp = h_all + (size_t)(wv*256 + t - 1)*768 + k0;
        #pragma unroll
        for (int i = 0; i < 12; ++i) hp[i] = hv[i];
      }
    }
    __syncthreads();
    if (t == 256) break;
    const int par = t & 1;
    const unsigned short tagp = (unsigned short)(t + 1);

    // ================= P1: a1 slice, tf slice =================
    {
      const int cg = tid >> 6, ks = tid & 63;
      float acc[4][4] = {};
      for (int i = 0; i < 12; ++i) {
        const int k = ks + 64*i;
        const float x0 = sX[k], x1 = sX[768+k], x2v = sX[1536+k], x3 = sX[2304+k];
        #pragma unroll
        for (int j = 0; j < 4; ++j) {
          float w;
          if (cg < 3) w = sRV0[(cg*4 + j)*768 + k];
          else        w = (j < 3) ? sRWt[j*768 + k] : 0.f;
          acc[j][0] += w*x0; acc[j][1] += w*x1; acc[j][2] += w*x2v; acc[j][3] += w*x3;
        }
      }
      #pragma unroll
      for (int j = 0; j < 4; ++j)
        #pragma unroll
        for (int bb = 0; bb < 4; ++bb) {
          const float v = wsum(acc[j][bb]);
          if (lane == 0) sRed[cg*16 + j*4 + bb] = v;
        }
      __syncthreads();
      if (tid < 16) {               // 16 a1 words: bb = tid&3, w = tid>>2
        const int bb = tid & 3, w = tid >> 2;
        float v[3];
        #pragma unroll
        for (int s = 0; s < 3; ++s) {
          const int c = w*3 + s;    // 0..11
          const float raw = sRed[(c >> 2)*16 + (c & 3)*4 + bb];
          v[s] = geluf(embV0[(size_t)(bb*256 + t)*3072 + g*12 + c] + 0.4f*raw);
        }
        st64(a1_64 + par*4096 + bb*1024 + g*4 + w, pk3t(v[0], v[1], v[2], tagp));
      } else if (tid < 20) {        // 4 tf words
        const int bb = tid - 16;
        st64(tf_64 + par*1024 + g*4 + bb,
             pk3t(sRed[48+bb], sRed[52+bb], sRed[56+bb], tagp));
      }
    }

    // ================= P2: target slice =================
    {
      // poll + stage a1 (16 tagged words per thread = whole 4x3072 a1)
      const u64* basep = a1_64 + par*4096;
      u64 x[16];
      bool ok;
      do {
        #pragma unroll
        for (int i = 0; i < 16; ++i) x[i] = ld64(basep + i*256 + tid);
        ok = true;
        #pragma unroll
        for (int i = 0; i < 16; ++i) ok &= ((unsigned short)(x[i] >> 48) == tagp);
      } while (__builtin_expect(!ok, 0));
      #pragma unroll
      for (int i = 0; i < 16; ++i) {
        const int widx = i*256 + tid;       // [0,4096)
        const int bb = widx >> 10, j = widx & 1023;
        sA1[bb*3072 + 3*j + 0] = (unsigned short)(x[i]);
        sA1[bb*3072 + 3*j + 1] = (unsigned short)(x[i] >> 16);
        sA1[bb*3072 + 3*j + 2] = (unsigned short)(x[i] >> 32);
      }
      __syncthreads();
      const int ks = lane, isub = wv;
      float acc[3][4] = {};
      for (int ip = 0; ip < 12; ++ip) {
        const int k = ks + 64*(isub + 4*ip);
        float xv[4];
        #pragma unroll
        for (int bb = 0; bb < 4; ++bb) xv[bb] = b2f(sA1[bb*3072 + k]);
        #pragma unroll
        for (int c = 0; c < 3; ++c) {
          const float w = sV1[c*3072 + k];
          acc[c][0] += w*xv[0]; acc[c][1] += w*xv[1]; acc[c][2] += w*xv[2]; acc[c][3] += w*xv[3];
        }
      }
      #pragma unroll
      for (int c = 0; c < 3; ++c)
        #pragma unroll
        for (int bb = 0; bb < 4; ++bb) {
          const float v = wsum(acc[c][bb]);
          if (lane == 0) sRed[isub*12 + c*4 + bb] = v;
        }
      __syncthreads();
      if (tid < 4) {
        const int bb = tid;
        float v[3];
        #pragma unroll
        for (int c = 0; c < 3; ++c) {
          float s = sRed[c*4+bb] + sRed[12 + c*4+bb] + sRed[24 + c*4+bb] + sRed[36 + c*4+bb];
          v[c] = geluf(s + b1[g*3 + c]);
        }
        st64(tg_64 + par*1024 + g*4 + bb, pk3t(v[0], v[1], v[2], tagp));
      }
    }

    // ================= P3: x2 EMA, cb, u slice =================
    {
      const int wb = par*1024 + lane*16 + wv;
      u64 wt4[4];
      bool ok;
      do {
        #pragma unroll
        for (int qq = 0; qq < 4; ++qq) wt4[qq] = ld64(tg_64 + wb + qq*4);
        ok = true;
        #pragma unroll
        for (int qq = 0; qq < 4; ++qq) ok &= ((unsigned short)(wt4[qq] >> 48) == tagp);
      } while (__builtin_expect(!ok, 0));
      float tv[12];
      #pragma unroll
      for (int qq = 0; qq < 4; ++qq) {
        tv[qq*3+0]=b2f((unsigned short)wt4[qq]);
        tv[qq*3+1]=b2f((unsigned short)(wt4[qq]>>16));
        tv[qq*3+2]=b2f((unsigned short)(wt4[qq]>>32));
      }
      const int xb = wv*768 + lane*12;
      float xv2[12];
      float ssqT = 0.f, ssqX = 0.f;
      #pragma unroll
      for (int i = 0; i < 12; ++i) {
        float xx = sX2[xb + i];
        const float tt = tv[i];
        #pragma unroll
        for (int rr = 0; rr < 10; ++rr) xx = 0.5f*xx + 0.5f*tt;
        sX2[xb + i] = xx; xv2[i] = xx;
        ssqT += tt*tt; ssqX += xx*xx;
      }
      ssqT = wsum(ssqT); ssqX = wsum(ssqX);
      const float invT = 1.0f / fmaxf(sqrtf(ssqT), 1e-12f);
      const float invX = 1.0f / fmaxf(sqrtf(ssqX), 1e-12f);
      #pragma unroll
      for (int i = 0; i < 12; ++i) sX[xb + i] = 0.5f*(tv[i]*invT + xv2[i]*invX);
      __syncthreads();
      const int ks = lane, isub = wv;
      float acc[3][4] = {};
      #pragma unroll
      for (int ip = 0; ip < 3; ++ip) {
        const int k = ks + 64*(isub + 4*ip);
        float xv[4];
        #pragma unroll
        for (int bb = 0; bb < 4; ++bb) xv[bb] = sX[bb*768 + k];
        #pragma unroll
        for (int c = 0; c < 3; ++c) {
          const float w = sW1[c*768 + k];
          acc[c][0] += w*xv[0]; acc[c][1] += w*xv[1]; acc[c][2] += w*xv[2]; acc[c][3] += w*xv[3];
        }
      }
      #pragma unroll
      for (int c = 0; c < 3; ++c)
        #pragma unroll
        for (int bb = 0; bb < 4; ++bb) {
          const float v = wsum(acc[c][bb]);
          if (lane == 0) sRed[isub*12 + c*4 + bb] = v;
        }
      __syncthreads();
      if (tid < 4) {
        const int bb = tid;
        float v[3];
        #pragma unroll
        for (int c = 0; c < 3; ++c) {
          float s = sRed[c*4+bb] + sRed[12 + c*4+bb] + sRed[24 + c*4+bb] + sRed[36 + c*4+bb];
          v[c] = geluf(s + c1[g*3 + c]);
        }
        st64(u_64 + par*1024 + g*4 + bb, pk3t(v[0], v[1], v[2], tagp));
      }
    }

    // ================= P4: cf slice, gv slice =================
    {
      const int wb = par*1024 + lane*16 + wv;
      u64 wu4[4];
      bool ok;
      do {
        #pragma unroll
        for (int qq = 0; qq < 4; ++qq) wu4[qq] = ld64(u_64 + wb + qq*4);
        ok = true;
        #pragma unroll
        for (int qq = 0; qq < 4; ++qq) ok &= ((unsigned short)(wu4[qq] >> 48) == tagp);
      } while (__builtin_expect(!ok, 0));
      const int xb = wv*768 + lane*12;
      #pragma unroll
      for (int qq = 0; qq < 4; ++qq) {
        sX[xb + qq*3 + 0] = b2f((unsigned short)wu4[qq]);
        sX[xb + qq*3 + 1] = b2f((unsigned short)(wu4[qq]>>16));
        sX[xb + qq*3 + 2] = b2f((unsigned short)(wu4[qq]>>32));
      }
      __syncthreads();
      const int ks = lane, isub = wv;
      float acc[6][4] = {};
      #pragma unroll
      for (int ip = 0; ip < 3; ++ip) {
        const int k = ks + 64*(isub + 4*ip);
        float xv[4];
        #pragma unroll
        for (int bb = 0; bb < 4; ++bb) xv[bb] = sX[bb*768 + k];
        #pragma unroll
        for (int c = 0; c < 6; ++c) {
          const float w = (c < 3) ? sW2[c*768 + k] : sW2G[(c-3)*768 + k];
          acc[c][0] += w*xv[0]; acc[c][1] += w*xv[1]; acc[c][2] += w*xv[2]; acc[c][3] += w*xv[3];
        }
      }
      #pragma unroll
      for (int c = 0; c < 6; ++c)
        #pragma unroll
        for (int bb = 0; bb < 4; ++bb) {
          const float v = wsum(acc[c][bb]);
          if (lane == 0) sRed[isub*24 + c*4 + bb] = v;
        }
      __syncthreads();
      if (tid < 8) {
        const int bb = tid & 3;
        if (tid < 4) {
          float vc[3];
          #pragma unroll
          for (int c = 0; c < 3; ++c) {
            float s = sRed[c*4+bb] + sRed[24 + c*4+bb] + sRed[48 + c*4+bb] + sRed[72 + c*4+bb];
            vc[c] = s + c2[g*3 + c];
          }
          st64(cf_64 + par*1024 + g*4 + bb, pk3t(vc[0], vc[1], vc[2], tagp));
        } else {
          float vg[3];
          #pragma unroll
          for (int c = 0; c < 3; ++c) {
            const int cc = c + 3;
            float s = sRed[cc*4+bb] + sRed[24 + cc*4+bb] + sRed[48 + cc*4+bb] + sRed[72 + cc*4+bb];
            vg[c] = s + embWg[(size_t)(bb*256 + t)*768 + g*3 + c] + gbias[g*3 + c];
          }
          st64(gv_64 + par*1024 + g*4 + bb, pk3t(vg[0], vg[1], vg[2], tagp));
        }
      }
    }
  }
}

// ---------------------------------------------------------------------------
// host
// ---------------------------------------------------------------------------
static void launch_gemm(const float* A, const void* B, float* C, const float* bias,
                        int M, int N, int bmode, hipStream_t st)
{
  const int ntiles = (N + 63) / 64;
  const int q = ntiles / 8, r = ntiles % 8;
  const int mtiles = M / 64;
  const int smax = (q + (r ? 1 : 0)) * mtiles;
  dim3 grid(8, smax);
  if (bmode == 0) gemm_kernel<0><<<grid, 256, 0, st>>>(A, B, C, bias, M, N, q, r);
  else            gemm_kernel<1><<<grid, 256, 0, st>>>(A, B, C, bias, M, N, q, r);
}

extern "C" void kernel_launch(void* const* d_in, const int* in_sizes, int n_in,
                              void* d_out, int out_size, void* d_ws, size_t ws_size,
                              hipStream_t stream)
{
  const int*   tok   = (const int*)d_in[0];
  const float* emb   = (const float*)d_in[1];
  const float* V0    = (const float*)d_in[2];
  const float* b0    = (const float*)d_in[3];
  const float* V1    = (const float*)d_in[4];
  const float* b1    = (const float*)d_in[5];
  const float* W1    = (const float*)d_in[6];
  const float* c1    = (const float*)d_in[7];
  const float* W2    = (const float*)d_in[8];
  const float* c2    = (const float*)d_in[9];
  const float* Wg    = (const float*)d_in[10];
  const float* bg    = (const float*)d_in[11];
  const float* Wt    = (const float*)d_in[12];
  const float* gamma = (const float*)d_in[13];
  const float* beta  = (const float*)d_in[14];
  const float* Wl    = (const float*)d_in[15];
  const float* Rw    = (const float*)d_in[16];

  float* outf = (float*)d_out;
  // scratch carved from d_out (all fully consumed before the final GEMM
  // overwrites d_out). float-slot offsets:
  float* emb_all = outf + 0;                    //  786432
  float* RV0     = outf + 786432;               // 2359296
  float* RWt     = outf + 3145728;              //  589824
  float* W2G     = outf + 3735552;              //  589824
  float* embV0   = outf + 4325376;              // 3145728
  float* embWg   = outf + 7471104;              //  786432
  float* gbias   = outf + 8257536;              //    1024
  unsigned short* V0T  = (unsigned short*)(outf + 8258560);   // 2359296 el
  unsigned short* WtT  = (unsigned short*)(outf + 9438208);   //  589824 el
  unsigned short* WgTT = (unsigned short*)(outf + 9733120);   //  589824 el
  unsigned short* WgBT = (unsigned short*)(outf + 10028032);  //  589824 el
  u64* a1_64 = (u64*)(outf + 10322944);   // 2*4096 u64 = 16384 floats
  u64* tf_64 = (u64*)(outf + 10339328);   // 2*1024 u64 =  4096 floats
  u64* tg_64 = (u64*)(outf + 10343424);
  u64* u_64  = (u64*)(outf + 10347520);
  u64* cf_64 = (u64*)(outf + 10351616);
  u64* gv_64 = (u64*)(outf + 10355712);

  // workspace: h_all (must survive into the final GEMM) + optional WlT
  float* h_all = (float*)d_ws;                                // 786432 f32
  unsigned short* WlT = (unsigned short*)((char*)d_ws + 786432*4);
  const bool bigws = ws_size >= (size_t)(786432*4) + (size_t)38597376*2 + 256;

  // transposed bf16 copies of GEMM B operands
  transpose_f2b<<<dim3(96, 24),   256, 0, stream>>>(V0, V0T, 3072, 0);
  transpose_f2b<<<dim3(24, 24),   256, 0, stream>>>(Wt, WtT, 768, 0);
  transpose_f2b<<<dim3(24, 24),   256, 0, stream>>>(Wg, WgTT, 768, 0);
  transpose_f2b<<<dim3(24, 24),   256, 0, stream>>>(Wg, WgBT, 768, 768);
  if (bigws)
    transpose_f2b<<<dim3(1572, 24), 256, 0, stream>>>(Wl, WlT, 50257, 0);

  embed_kernel<<<1024, 256, 0, stream>>>(tok, emb, emb_all);
  gbias_kernel<<<3, 256, 0, stream>>>(c2, Wg, gbias);

  // fused-weight + per-token precompute GEMMs (bf16 MFMA, fp32 out)
  launch_gemm(Rw,      V0T,  RV0,   nullptr, 768,  3072, 0, stream);
  launch_gemm(Rw,      WtT,  RWt,   nullptr, 768,  768,  0, stream);
  launch_gemm(W2,      WgBT, W2G,   nullptr, 768,  768,  0, stream);
  launch_gemm(emb_all, V0T,  embV0, b0,      1024, 3072, 0, stream);
  launch_gemm(emb_all, WgTT, embWg, bg,      1024, 768,  0, stream);

  // the sequential part
  recur_kernel<<<256, 256, 0, stream>>>(
      RV0, RWt, W1, W2, W2G, V1, embV0, embWg, gbias, emb_all,
      b1, c1, c2, gamma, beta, h_all,
      a1_64, tf_64, tg_64, u_64, cf_64, gv_64);

  // deferred lm_head: logits[b*256+t][v] = h_all @ Wl
  if (bigws) launch_gemm(h_all, WlT, outf, nullptr, 1024, 50257, 0, stream);
  else       launch_gemm(h_all, Wl,  outf, nullptr, 1024, 50257, 1, stream);
}